// Round 4
// baseline (196.355 us; speedup 1.0000x reference)
//
#include <hip/hip_runtime.h>
#include <hip/hip_bf16.h>
#include <math.h>

#define BDIM 512
#define DDIM 512
#define SPLIT 4     // blocks per row in pair_loss

typedef __attribute__((ext_vector_type(8))) short bfrag;   // 8 bf16 = 4 VGPRs
typedef __attribute__((ext_vector_type(4))) float ffrag;   // 4 fp32 acc

// load 8 consecutive fp32 and convert to a bf16 MFMA fragment in registers
__device__ __forceinline__ bfrag load_cvt8(const float* __restrict__ p) {
    float4 u = *(const float4*)p;
    float4 v = *(const float4*)(p + 4);
    union { __hip_bfloat16 h[8]; bfrag f; } cv;
    cv.h[0] = __float2bfloat16(u.x); cv.h[1] = __float2bfloat16(u.y);
    cv.h[2] = __float2bfloat16(u.z); cv.h[3] = __float2bfloat16(u.w);
    cv.h[4] = __float2bfloat16(v.x); cv.h[5] = __float2bfloat16(v.y);
    cv.h[6] = __float2bfloat16(v.z); cv.h[7] = __float2bfloat16(v.w);
    return cv.f;
}

// ---------------- sim = (A . A^T) / 0.07 via bf16 MFMA, fp32 cvt inline ----
// One wave per 16x16 output tile, fragments built straight from global fp32
// (L2-resident, 1 MB). For C = A.A^T both A-frag (A[m=lane&15][k=quad*8+j])
// and B-frag (A[n=lane&15][k=quad*8+j]) are one contiguous 32B row chunk per
// lane: no LDS, no transpose, no separate convert pass. Also zero-inits the
// global accumulators + completion counter (stream-ordered before pair_loss).
__global__ __launch_bounds__(256) void gemm_mfma(const float* __restrict__ A,
                                                 float* __restrict__ S,
                                                 double* __restrict__ acc,
                                                 unsigned* __restrict__ ctr) {
    if (blockIdx.x == 0 && blockIdx.y == 0 && threadIdx.x == 0) {
        acc[0] = 0.0; acc[1] = 0.0; *ctr = 0u;
    }
    const int tid = threadIdx.x;
    const int w = tid >> 6, lane = tid & 63;
    const int quad = lane >> 4, r = lane & 15;
    const int m0 = blockIdx.y * 64 + w * 16;   // 4 waves stacked in M
    const int n0 = blockIdx.x * 16;            // shared across waves -> L1 reuse
    const float* arow = A + (m0 + r) * DDIM + quad * 8;
    const float* brow = A + (n0 + r) * DDIM + quad * 8;
    ffrag c = {0.f, 0.f, 0.f, 0.f};
#pragma unroll
    for (int k = 0; k < DDIM; k += 32) {
        bfrag af = load_cvt8(arow + k);
        bfrag bf = load_cvt8(brow + k);
        c = __builtin_amdgcn_mfma_f32_16x16x32_bf16(af, bf, c, 0, 0, 0);
    }
    const float sc = 1.0f / 0.07f;
    // C/D layout: row = quad*4 + reg, col = lane&15 (m89-verified mapping)
#pragma unroll
    for (int rg = 0; rg < 4; ++rg)
        S[(m0 + quad * 4 + rg) * BDIM + n0 + r] = c[rg] * sc;
}

__device__ __forceinline__ float softplus_f(float z) {
    // softplus(z) = -log_sigmoid(-z), stable; returns exactly 0 for z = -inf
    return fmaxf(z, 0.0f) + __logf(1.0f + __expf(-fabsf(z)));
}

// ---------------- pairwise softplus loss + finalize ----------------
// SPLIT blocks per row. Ballot compaction into pos/neg sim values. ns padded
// to 512 with -INF and ps with +INF (softplus contributes exactly 0), so each
// thread hoists its 2 ns values into registers and the hot loop is
// 1 ds_read_b128 + 8 register-resident softplus with 8 independent chains.
// Last block to finish (device-scope counter) computes the final scalar.
__global__ __launch_bounds__(256) void pair_loss(const float* __restrict__ S,
                                                 const float* __restrict__ mask,
                                                 const int* __restrict__ sel,
                                                 double* __restrict__ acc,
                                                 unsigned* __restrict__ ctr,
                                                 float* __restrict__ out) {
    const int i = blockIdx.x >> 2;     // row
    const int q = blockIdx.x & 3;      // p-chunk
    const int tid = threadIdx.x;
    const int lane = tid & 63, wave = tid >> 6;
    const bool active = (sel[i] != 0);   // sel multiplies both masks
    if (active) {
        __shared__ float sm[BDIM];
        __shared__ __align__(16) float ps[BDIM + 4];
        __shared__ float ns[BDIM];
        __shared__ int cnt[2];
        __shared__ float wsum[4];
        if (tid < 2) cnt[tid] = 0;
        *(float2*)&sm[tid * 2] = *(const float2*)&S[i * BDIM + tid * 2];
        __syncthreads();
#pragma unroll
        for (int rr = 0; rr < 2; ++rr) {
            const int p = tid + rr * 256;
            const float m = mask[i * BDIM + p];     // exactly 0.0f or 1.0f
            const bool ok  = (p != i);              // logits_mask kills diagonal
            const bool isp = ok && (m != 0.0f);
            const bool isn = ok && (m == 0.0f);
            unsigned long long bp = __ballot(isp);
            unsigned long long bn = __ballot(isn);
            unsigned long long lower = (1ULL << lane) - 1ULL;
            int pbase = 0, nbase = 0;
            if (lane == 0) {
                pbase = atomicAdd(&cnt[0], __popcll(bp));
                nbase = atomicAdd(&cnt[1], __popcll(bn));
            }
            pbase = __shfl(pbase, 0, 64);
            nbase = __shfl(nbase, 0, 64);
            if (isp) ps[pbase + __popcll(bp & lower)] = sm[p];
            if (isn) ns[nbase + __popcll(bn & lower)] = sm[p];
        }
        __syncthreads();
        const int npos = cnt[0], nneg = cnt[1];
        if (tid < 4) ps[npos + tid] = INFINITY;               // +INF pad -> 0
        for (int x = nneg + tid; x < BDIM; x += 256) ns[x] = -INFINITY;  // -INF pad -> 0
        __syncthreads();
        const float sn0 = ns[tid];
        const float sn1 = ns[tid + 256];
        // 4-aligned chunk boundaries partitioning [0, npos)
        int p0 = (q == 0) ? 0 : min(npos, ((q * npos) / SPLIT + 3) & ~3);
        int p1 = (q == SPLIT - 1) ? npos : min(npos, (((q + 1) * npos) / SPLIT + 3) & ~3);
        float l0 = 0.f, l1 = 0.f, l2 = 0.f, l3 = 0.f;
        float l4 = 0.f, l5 = 0.f, l6 = 0.f, l7 = 0.f;
        for (int pp = p0; pp < p1; pp += 4) {
            float4 sp = *(const float4*)&ps[pp];
            l0 += softplus_f(sn0 - sp.x);
            l1 += softplus_f(sn0 - sp.y);
            l2 += softplus_f(sn0 - sp.z);
            l3 += softplus_f(sn0 - sp.w);
            l4 += softplus_f(sn1 - sp.x);
            l5 += softplus_f(sn1 - sp.y);
            l6 += softplus_f(sn1 - sp.z);
            l7 += softplus_f(sn1 - sp.w);
        }
        float local = ((l0 + l1) + (l2 + l3)) + ((l4 + l5) + (l6 + l7));
#pragma unroll
        for (int off = 32; off > 0; off >>= 1) local += __shfl_down(local, off, 64);
        if (lane == 0) wsum[wave] = local;
        __syncthreads();
        if (tid == 0) {
            double tot = (double)wsum[0] + (double)wsum[1] + (double)wsum[2] + (double)wsum[3];
            atomicAdd(&acc[0], tot);
            if (q == 0) atomicAdd(&acc[1], (double)npos * (double)nneg);
        }
    }
    // completion counter: every block participates; last one finalizes
    __threadfence();
    if (tid == 0) {
        unsigned done = atomicAdd(ctr, 1u);
        if (done == gridDim.x - 1) {
            __threadfence();
            double ls = acc[0], pn = acc[1];
            double loss = (pn > 0.0) ? ls / fmax(pn, 1.0) : ls;
            out[0] = (float)loss;
        }
    }
}

extern "C" void kernel_launch(void* const* d_in, const int* in_sizes, int n_in,
                              void* d_out, int out_size, void* d_ws, size_t ws_size,
                              hipStream_t stream) {
    const float* feat = (const float*)d_in[0];   // (512,1,512) == anchor (512,512)
    const float* mask = (const float*)d_in[1];   // (512,512) fp32 {0,1}
    const int*   sel  = (const int*)d_in[2];     // (512,) bool -> int32
    float* out = (float*)d_out;

    char* ws = (char*)d_ws;
    float* S = (float*)ws;                                        // 1 MB
    double* acc = (double*)(ws + BDIM * BDIM * sizeof(float));    // 16 B
    unsigned* ctr = (unsigned*)(ws + BDIM * BDIM * sizeof(float) + 16);

    gemm_mfma<<<dim3(BDIM / 16, BDIM / 64), 256, 0, stream>>>(feat, S, acc, ctr);
    pair_loss<<<BDIM * SPLIT, 256, 0, stream>>>(S, mask, sel, acc, ctr, out);
}

// Round 5
// 95.051 us; speedup vs baseline: 2.0658x; 2.0658x over previous
//
#include <hip/hip_runtime.h>
#include <hip/hip_bf16.h>
#include <math.h>

#define BDIM 512
#define DDIM 512
#define SPLIT 4     // blocks per row in pair_loss

typedef __attribute__((ext_vector_type(8))) short bfrag;   // 8 bf16 = 4 VGPRs
typedef __attribute__((ext_vector_type(4))) float ffrag;   // 4 fp32 acc

// load 8 consecutive fp32 and convert to a bf16 MFMA fragment in registers
__device__ __forceinline__ bfrag load_cvt8(const float* __restrict__ p) {
    float4 u = *(const float4*)p;
    float4 v = *(const float4*)(p + 4);
    union { __hip_bfloat16 h[8]; bfrag f; } cv;
    cv.h[0] = __float2bfloat16(u.x); cv.h[1] = __float2bfloat16(u.y);
    cv.h[2] = __float2bfloat16(u.z); cv.h[3] = __float2bfloat16(u.w);
    cv.h[4] = __float2bfloat16(v.x); cv.h[5] = __float2bfloat16(v.y);
    cv.h[6] = __float2bfloat16(v.z); cv.h[7] = __float2bfloat16(v.w);
    return cv.f;
}

// ---------------- sim = (A . A^T) / 0.07 via bf16 MFMA, fp32 cvt inline ----
// One wave per 16x16 output tile, fragments built straight from global fp32
// (L2-resident, 1 MB). For C = A.A^T both A-frag (A[m=lane&15][k=quad*8+j])
// and B-frag (A[n=lane&15][k=quad*8+j]) are one contiguous 32B row chunk per
// lane: no LDS, no transpose, no separate convert pass. Also zero-inits the
// global accumulators (stream-ordered before pair_loss reads them).
__global__ __launch_bounds__(256) void gemm_mfma(const float* __restrict__ A,
                                                 float* __restrict__ S,
                                                 double* __restrict__ acc) {
    if (blockIdx.x == 0 && blockIdx.y == 0 && threadIdx.x == 0) {
        acc[0] = 0.0; acc[1] = 0.0;
    }
    const int tid = threadIdx.x;
    const int w = tid >> 6, lane = tid & 63;
    const int quad = lane >> 4, r = lane & 15;
    const int m0 = blockIdx.y * 64 + w * 16;   // 4 waves stacked in M
    const int n0 = blockIdx.x * 16;            // shared across waves -> L1 reuse
    const float* arow = A + (m0 + r) * DDIM + quad * 8;
    const float* brow = A + (n0 + r) * DDIM + quad * 8;
    ffrag c = {0.f, 0.f, 0.f, 0.f};
#pragma unroll
    for (int k = 0; k < DDIM; k += 32) {
        bfrag af = load_cvt8(arow + k);
        bfrag bf = load_cvt8(brow + k);
        c = __builtin_amdgcn_mfma_f32_16x16x32_bf16(af, bf, c, 0, 0, 0);
    }
    const float sc = 1.0f / 0.07f;
    // C/D layout: row = quad*4 + reg, col = lane&15 (m89-verified mapping)
#pragma unroll
    for (int rg = 0; rg < 4; ++rg)
        S[(m0 + quad * 4 + rg) * BDIM + n0 + r] = c[rg] * sc;
}

__device__ __forceinline__ float softplus_f(float z) {
    // softplus(z) = -log_sigmoid(-z), stable; exactly 0 at z = -inf, no NaN
    return fmaxf(z, 0.0f) + __logf(1.0f + __expf(-fabsf(z)));
}

// ---------------- pairwise softplus loss ----------------
// SPLIT blocks per row; sel==0 rows exit immediately. Ballot compaction of
// pos/neg sim values into LDS (order-free). ns padded to 512 with -INF and
// ps with +INF (softplus contributes exactly 0), so ns lives in registers and
// the hot loop is 1 ds_read_b128 + 4-or-8 register-resident softplus chains
// (block-uniform branch on nneg<=256 halves the padding waste).
// NO device-scope fences here (R4 lesson: they cost ~120 us in L2 thrash).
__global__ __launch_bounds__(256) void pair_loss(const float* __restrict__ S,
                                                 const float* __restrict__ mask,
                                                 const int* __restrict__ sel,
                                                 double* __restrict__ acc) {
    const int i = blockIdx.x >> 2;     // row
    const int q = blockIdx.x & 3;      // p-chunk
    if (sel[i] == 0) return;           // sel multiplies both masks
    __shared__ __align__(16) float ps[BDIM + 4];
    __shared__ float ns[BDIM];
    __shared__ int cnt[2];
    __shared__ float wsum[4];
    const int tid = threadIdx.x;
    const int lane = tid & 63, wave = tid >> 6;
    if (tid < 2) cnt[tid] = 0;
    __syncthreads();
#pragma unroll
    for (int rr = 0; rr < 2; ++rr) {
        const int p = tid + rr * 256;
        const float v = S[i * BDIM + p];        // coalesced, L2-resident
        const float m = mask[i * BDIM + p];     // exactly 0.0f or 1.0f
        const bool ok  = (p != i);              // logits_mask kills diagonal
        const bool isp = ok && (m != 0.0f);
        const bool isn = ok && (m == 0.0f);
        unsigned long long bp = __ballot(isp);
        unsigned long long bn = __ballot(isn);
        unsigned long long lower = (1ULL << lane) - 1ULL;
        int pbase = 0, nbase = 0;
        if (lane == 0) {
            pbase = atomicAdd(&cnt[0], __popcll(bp));
            nbase = atomicAdd(&cnt[1], __popcll(bn));
        }
        pbase = __shfl(pbase, 0, 64);
        nbase = __shfl(nbase, 0, 64);
        if (isp) ps[pbase + __popcll(bp & lower)] = v;
        if (isn) ns[nbase + __popcll(bn & lower)] = v;
    }
    __syncthreads();
    const int npos = cnt[0], nneg = cnt[1];
    if (tid < 4) ps[npos + tid] = INFINITY;                          // +INF pad -> 0
    for (int x = nneg + tid; x < BDIM; x += 256) ns[x] = -INFINITY;  // -INF pad -> 0
    __syncthreads();
    const float sn0 = ns[tid];
    const float sn1 = ns[tid + 256];
    // 4-aligned chunk boundaries partitioning [0, npos)
    int p0 = (q == 0) ? 0 : min(npos, ((q * npos) / SPLIT + 3) & ~3);
    int p1 = (q == SPLIT - 1) ? npos : min(npos, (((q + 1) * npos) / SPLIT + 3) & ~3);
    float l0 = 0.f, l1 = 0.f, l2 = 0.f, l3 = 0.f;
    float l4 = 0.f, l5 = 0.f, l6 = 0.f, l7 = 0.f;
    if (nneg <= 256) {      // block-uniform: all real ns in sn0
        for (int pp = p0; pp < p1; pp += 4) {
            float4 sp = *(const float4*)&ps[pp];
            l0 += softplus_f(sn0 - sp.x);
            l1 += softplus_f(sn0 - sp.y);
            l2 += softplus_f(sn0 - sp.z);
            l3 += softplus_f(sn0 - sp.w);
        }
    } else {
        for (int pp = p0; pp < p1; pp += 4) {
            float4 sp = *(const float4*)&ps[pp];
            l0 += softplus_f(sn0 - sp.x);
            l1 += softplus_f(sn0 - sp.y);
            l2 += softplus_f(sn0 - sp.z);
            l3 += softplus_f(sn0 - sp.w);
            l4 += softplus_f(sn1 - sp.x);
            l5 += softplus_f(sn1 - sp.y);
            l6 += softplus_f(sn1 - sp.z);
            l7 += softplus_f(sn1 - sp.w);
        }
    }
    float local = ((l0 + l1) + (l2 + l3)) + ((l4 + l5) + (l6 + l7));
#pragma unroll
    for (int off = 32; off > 0; off >>= 1) local += __shfl_down(local, off, 64);
    if (lane == 0) wsum[wave] = local;
    __syncthreads();
    if (tid == 0) {
        double tot = (double)wsum[0] + (double)wsum[1] + (double)wsum[2] + (double)wsum[3];
        atomicAdd(&acc[0], tot);
        if (q == 0) atomicAdd(&acc[1], (double)npos * (double)nneg);
    }
}

__global__ void finalize(const double* __restrict__ acc, float* __restrict__ out) {
    double ls = acc[0], pn = acc[1];
    double loss = (pn > 0.0) ? ls / fmax(pn, 1.0) : ls;
    out[0] = (float)loss;
}

extern "C" void kernel_launch(void* const* d_in, const int* in_sizes, int n_in,
                              void* d_out, int out_size, void* d_ws, size_t ws_size,
                              hipStream_t stream) {
    const float* feat = (const float*)d_in[0];   // (512,1,512) == anchor (512,512)
    const float* mask = (const float*)d_in[1];   // (512,512) fp32 {0,1}
    const int*   sel  = (const int*)d_in[2];     // (512,) bool -> int32
    float* out = (float*)d_out;

    char* ws = (char*)d_ws;
    float* S = (float*)ws;                                        // 1 MB
    double* acc = (double*)(ws + BDIM * BDIM * sizeof(float));    // 16 B

    gemm_mfma<<<dim3(BDIM / 16, BDIM / 64), 256, 0, stream>>>(feat, S, acc);
    pair_loss<<<BDIM * SPLIT, 256, 0, stream>>>(S, mask, sel, acc);
    finalize<<<1, 1, 0, stream>>>(acc, out);
}